// Round 1
// baseline (221.435 us; speedup 1.0000x reference)
//
#include <hip/hip_runtime.h>
#include <float.h>
#include <math.h>

// Problem constants (match reference)
#define BATCH 1024
#define NS    2048      // S: samples per row (index 0 = positive)
#define EMB   128       // E
#define THREADS 256     // 4 waves/block

// Layout: one block per batch row b.
// Thread t: e_part = t&3 (which quarter-of-row), s_local = t>>2 (which sample).
// Each quad (4 lanes) computes one dot<inputs[b], weight[id]> of length 128:
//   lane covers elements {k*16 + e_part*4 + j : k=0..7, j=0..3} via 8 float4 loads,
//   so per load-instruction a quad reads a contiguous 64B segment (line-aligned;
//   weight rows are 512B). Quad-reduce = 2 shfl_xor steps.
// Online logsumexp (m,l) per thread; quad-dedup; wave butterfly; LDS combine;
// one atomicAdd per block into the scalar output.
__global__ __launch_bounds__(THREADS) void sampled_ce_kernel(
    const float* __restrict__ inputs,     // [B, E]
    const float* __restrict__ weight,     // [V, E]
    const float* __restrict__ bias,       // [V]
    const int*   __restrict__ sample_ids, // [B, S]
    float* __restrict__ out)              // [1]
{
    const int b = blockIdx.x;
    const int t = threadIdx.x;
    const int e_part  = t & 3;
    const int s_local = t >> 2;   // 0..63

    __shared__ float s_in[EMB];
    __shared__ float s_red[8];    // (m,l) per wave
    __shared__ float s_logit0;

    // Stage inputs[b] into LDS (32 float4 = 128 floats)
    if (t < EMB / 4) {
        ((float4*)s_in)[t] = ((const float4*)(inputs + (size_t)b * EMB))[t];
    }
    __syncthreads();

    // Pull this lane's 8 float4 input fragments into registers (reused 32x).
    // Same-address across quads -> LDS broadcast, no bank conflicts.
    float4 cin[8];
#pragma unroll
    for (int k = 0; k < 8; ++k) {
        cin[k] = ((const float4*)s_in)[k * 4 + e_part];
    }

    float m = -FLT_MAX;
    float l = 0.0f;

    const int* ids_row = sample_ids + (size_t)b * NS;

    for (int it = 0; it < NS / 64; ++it) {
        const int s = it * 64 + s_local;
        const int id = ids_row[s];
        const float4* wr = (const float4*)(weight + (size_t)id * EMB);

        float acc = 0.0f;
#pragma unroll
        for (int k = 0; k < 8; ++k) {
            float4 w = wr[k * 4 + e_part];
            acc += w.x * cin[k].x + w.y * cin[k].y
                 + w.z * cin[k].z + w.w * cin[k].w;
        }
        // Quad reduction: all 4 lanes end up with the full dot.
        acc += __shfl_xor(acc, 1, 64);
        acc += __shfl_xor(acc, 2, 64);
        const float logit = acc + bias[id];

        // Online logsumexp update (all 4 lanes of a quad track identically).
        const float nm = fmaxf(m, logit);
        l = l * __expf(m - nm) + __expf(logit - nm);
        m = nm;

        if (it == 0 && s_local == 0 && e_part == 0) {
            s_logit0 = logit;   // logits[b, 0], written by thread 0
        }
    }

    // Deduplicate: only e_part==0 lanes contribute their (m,l).
    if (e_part != 0) { m = -FLT_MAX; l = 0.0f; }

    // Wave-level butterfly combine of (m,l) across 64 lanes.
#pragma unroll
    for (int off = 1; off < 64; off <<= 1) {
        const float om = __shfl_xor(m, off, 64);
        const float ol = __shfl_xor(l, off, 64);
        const float nm = fmaxf(m, om);
        // note: if both m,om == -FLT_MAX, expf(0)=1 and l stays 0 (no NaN)
        l = l * __expf(m - nm) + ol * __expf(om - nm);
        m = nm;
    }

    const int wave = t >> 6;
    if ((t & 63) == 0) {
        s_red[wave * 2 + 0] = m;
        s_red[wave * 2 + 1] = l;
    }
    __syncthreads();

    if (t == 0) {
        float M = s_red[0];
        float L = s_red[1];
#pragma unroll
        for (int w = 1; w < 4; ++w) {
            const float om = s_red[w * 2 + 0];
            const float ol = s_red[w * 2 + 1];
            const float nm = fmaxf(M, om);
            L = L * __expf(M - nm) + ol * __expf(om - nm);
            M = nm;
        }
        const float lse = M + __logf(L);
        atomicAdd(out, (lse - s_logit0) * (1.0f / (float)BATCH));
    }
}

extern "C" void kernel_launch(void* const* d_in, const int* in_sizes, int n_in,
                              void* d_out, int out_size, void* d_ws, size_t ws_size,
                              hipStream_t stream) {
    const float* inputs     = (const float*)d_in[0];  // [B, E] fp32
    const float* weight     = (const float*)d_in[1];  // [V, E] fp32
    const float* bias       = (const float*)d_in[2];  // [V]    fp32
    const int*   sample_ids = (const int*)d_in[3];    // [B, S] int32
    float* out = (float*)d_out;                       // scalar fp32

    // d_out is poisoned 0xAA before every launch; zero it for the atomic sum.
    hipMemsetAsync(out, 0, sizeof(float), stream);

    sampled_ce_kernel<<<dim3(BATCH), dim3(THREADS), 0, stream>>>(
        inputs, weight, bias, sample_ids, out);
}